// Round 1
// baseline (830.584 us; speedup 1.0000x reference)
//
#include <hip/hip_runtime.h>
#include <hip/hip_bf16.h>
#include <math.h>

#define DEVI static __device__ __forceinline__

typedef __attribute__((ext_vector_type(4))) float f32x4;
typedef __attribute__((ext_vector_type(8))) short bf16x8;
typedef __attribute__((ext_vector_type(4))) short bf16x4;

constexpr int Bc = 4, Lc = 2048, Sc = 2048, Dc = 1024, Hc = 8, Ec = 128, UVc = 128;
constexpr int HEc = Hc * Ec;   // 1024
constexpr int BLc = Bc * Lc;   // 8192

DEVI unsigned f2bf_bits(float f) {
  unsigned u = __builtin_bit_cast(unsigned, f);
  return (u + 0x7FFFu + ((u >> 16) & 1u)) >> 16;
}
DEVI short f2bf(float f) { return (short)f2bf_bits(f); }
DEVI float bf2f(short s) {
  return __builtin_bit_cast(float, (unsigned)((unsigned short)s) << 16);
}
DEVI float gelu_f(float x) { return 0.5f * x * (1.0f + erff(x * 0.7071067811865476f)); }

// ---------------- prep: weight transpose f32[K][N] -> bf16 WT[N][K] ----------------
__global__ void wt_trans_kernel(const float* __restrict__ W, short* __restrict__ WT) {
  __shared__ float t[32][33];
  int tx = threadIdx.x, ty = threadIdx.y;
  int n0 = blockIdx.x * 32, k0 = blockIdx.y * 32;
#pragma unroll
  for (int i = 0; i < 4; i++) {
    int r = ty + i * 8;
    t[r][tx] = W[(size_t)(k0 + r) * 1024 + n0 + tx];
  }
  __syncthreads();
#pragma unroll
  for (int i = 0; i < 4; i++) {
    int r = ty + i * 8;
    WT[(size_t)(n0 + r) * 1024 + k0 + tx] = f2bf(t[tx][r]);
  }
}

// ---------------- prep: rope tables [2048][512] ----------------
__global__ void rope_table_kernel(float* __restrict__ ct, float* __restrict__ st) {
  int idx = blockIdx.x * 256 + threadIdx.x;  // 2048*512 total
  int t = idx >> 9, i = idx & 511;
  float inv = expf((float)i * (-9.210340371976184f / 512.0f));  // 10000^(-i/512)
  float ang = (float)t * inv;
  float sv, cv;
  sincosf(ang, &sv, &cv);
  ct[idx] = cv;
  st[idx] = sv;
}

// ---------------- GEMM: C = act(A @ W + bias), W given as WT[N][K] bf16 ----------------
template <bool A_F32, bool GELU_BF16>
__global__ __launch_bounds__(256, 2) void gemm_kernel(
    const void* __restrict__ Aptr, const short* __restrict__ BT,
    const float* __restrict__ bias, void* __restrict__ Cptr, int M, int N, int K) {
  __shared__ short As[128][40];
  __shared__ short Bs[128][40];
  const int tid = threadIdx.x;
  const int wave = tid >> 6, lane = tid & 63;
  const int lquad = lane >> 4, l15 = lane & 15;
  const int m0 = blockIdx.x * 128, n0 = blockIdx.y * 128;
  const int wr = wave >> 1, wc = wave & 1;
  f32x4 acc[4][4] = {};
  const float* Af = (const float*)Aptr;
  const short* Ab = (const short*)Aptr;

  for (int kt = 0; kt < K; kt += 32) {
#pragma unroll
    for (int c0 = 0; c0 < 2; c0++) {
      int c = tid + c0 * 256;
      int row = c >> 2, seg = (c & 3) * 8;
      if (A_F32) {
        const float* src = Af + (size_t)(m0 + row) * K + kt + seg;
        float4 f1 = *reinterpret_cast<const float4*>(src);
        float4 f2 = *reinterpret_cast<const float4*>(src + 4);
        uint4 pk;
        pk.x = f2bf_bits(f1.x) | (f2bf_bits(f1.y) << 16);
        pk.y = f2bf_bits(f1.z) | (f2bf_bits(f1.w) << 16);
        pk.z = f2bf_bits(f2.x) | (f2bf_bits(f2.y) << 16);
        pk.w = f2bf_bits(f2.z) | (f2bf_bits(f2.w) << 16);
        *reinterpret_cast<uint4*>(&As[row][seg]) = pk;
      } else {
        uint4 ar = *reinterpret_cast<const uint4*>(Ab + (size_t)(m0 + row) * K + kt + seg);
        *reinterpret_cast<uint4*>(&As[row][seg]) = ar;
      }
      uint4 br = *reinterpret_cast<const uint4*>(BT + (size_t)(n0 + row) * K + kt + seg);
      *reinterpret_cast<uint4*>(&Bs[row][seg]) = br;
    }
    __syncthreads();
    const int kb = 4 * lquad;
    bf16x8 a[4], b[4];
#pragma unroll
    for (int f = 0; f < 4; f++) {
      int ra = wr * 64 + f * 16 + l15;
      bf16x4 lo = *reinterpret_cast<bf16x4*>(&As[ra][kb]);
      bf16x4 hi = *reinterpret_cast<bf16x4*>(&As[ra][kb + 16]);
      a[f] = __builtin_shufflevector(lo, hi, 0, 1, 2, 3, 4, 5, 6, 7);
      int rb = wc * 64 + f * 16 + l15;
      bf16x4 lo2 = *reinterpret_cast<bf16x4*>(&Bs[rb][kb]);
      bf16x4 hi2 = *reinterpret_cast<bf16x4*>(&Bs[rb][kb + 16]);
      b[f] = __builtin_shufflevector(lo2, hi2, 0, 1, 2, 3, 4, 5, 6, 7);
    }
#pragma unroll
    for (int mf = 0; mf < 4; mf++)
#pragma unroll
      for (int nf = 0; nf < 4; nf++)
        acc[mf][nf] = __builtin_amdgcn_mfma_f32_16x16x32_bf16(a[mf], b[nf], acc[mf][nf], 0, 0, 0);
    __syncthreads();
  }
#pragma unroll
  for (int mf = 0; mf < 4; mf++) {
#pragma unroll
    for (int nf = 0; nf < 4; nf++) {
      int mrow = m0 + wr * 64 + mf * 16 + 4 * lquad;
      int ncol = n0 + wc * 64 + nf * 16 + l15;
      float bval = bias[ncol];
#pragma unroll
      for (int r = 0; r < 4; r++) {
        float v = acc[mf][nf][r] + bval;
        if (GELU_BF16) {
          ((short*)Cptr)[(size_t)(mrow + r) * N + ncol] = f2bf(gelu_f(v));
        } else {
          ((float*)Cptr)[(size_t)(mrow + r) * N + ncol] = v;
        }
      }
    }
  }
}

// ---------------- rope apply: qk_gelu -> q, k (scale-offset + interleaved rotary) ----------------
__global__ void rope_apply_kernel(const short* __restrict__ qkg,
                                  const float* __restrict__ ct, const float* __restrict__ st,
                                  const float* __restrict__ qg, const float* __restrict__ qb,
                                  const float* __restrict__ kg, const float* __restrict__ kb,
                                  short* __restrict__ qo, short* __restrict__ ko) {
  int tid = blockIdx.x * 256 + threadIdx.x;
  size_t base = (size_t)tid * 8;
  int bl = (int)(base >> 10);
  int rem = (int)(base & 1023);
  int e0 = rem & 127;
  int t = bl & 2047;
  int pf = rem >> 1;  // flat pair index
  uint4 raw = *reinterpret_cast<const uint4*>(qkg + base);
  short sh[8];
  *reinterpret_cast<uint4*>(sh) = raw;
  float4 c4 = *reinterpret_cast<const float4*>(ct + (size_t)t * 512 + pf);
  float4 s4 = *reinterpret_cast<const float4*>(st + (size_t)t * 512 + pf);
  float4 qga = *reinterpret_cast<const float4*>(qg + e0);
  float4 qgb = *reinterpret_cast<const float4*>(qg + e0 + 4);
  float4 qba = *reinterpret_cast<const float4*>(qb + e0);
  float4 qbb = *reinterpret_cast<const float4*>(qb + e0 + 4);
  float4 kga = *reinterpret_cast<const float4*>(kg + e0);
  float4 kgb = *reinterpret_cast<const float4*>(kg + e0 + 4);
  float4 kba = *reinterpret_cast<const float4*>(kb + e0);
  float4 kbb = *reinterpret_cast<const float4*>(kb + e0 + 4);
  float C[4] = {c4.x, c4.y, c4.z, c4.w};
  float Sn[4] = {s4.x, s4.y, s4.z, s4.w};
  float QG[8] = {qga.x, qga.y, qga.z, qga.w, qgb.x, qgb.y, qgb.z, qgb.w};
  float QB[8] = {qba.x, qba.y, qba.z, qba.w, qbb.x, qbb.y, qbb.z, qbb.w};
  float KG[8] = {kga.x, kga.y, kga.z, kga.w, kgb.x, kgb.y, kgb.z, kgb.w};
  float KB[8] = {kba.x, kba.y, kba.z, kba.w, kbb.x, kbb.y, kbb.z, kbb.w};
  short qsh[8], ksh[8];
#pragma unroll
  for (int j = 0; j < 4; j++) {
    float x0 = bf2f(sh[2 * j]), x1 = bf2f(sh[2 * j + 1]);
    float q0 = x0 * QG[2 * j] + QB[2 * j];
    float q1 = x1 * QG[2 * j + 1] + QB[2 * j + 1];
    qsh[2 * j] = f2bf(q0 * C[j] - q1 * Sn[j]);
    qsh[2 * j + 1] = f2bf(q1 * C[j] + q0 * Sn[j]);
    float k0v = x0 * KG[2 * j] + KB[2 * j];
    float k1v = x1 * KG[2 * j + 1] + KB[2 * j + 1];
    ksh[2 * j] = f2bf(k0v * C[j] - k1v * Sn[j]);
    ksh[2 * j + 1] = f2bf(k1v * C[j] + k0v * Sn[j]);
  }
  *reinterpret_cast<uint4*>(qo + base) = *reinterpret_cast<uint4*>(qsh);
  *reinterpret_cast<uint4*>(ko + base) = *reinterpret_cast<uint4*>(ksh);
}

// ---------------- v transpose: [B][S][H][UV] -> [B][H][UV][S] (bf16) ----------------
__global__ void vtrans_kernel(const short* __restrict__ v, short* __restrict__ vT) {
  __shared__ short t[32][33];
  int bh = blockIdx.z;
  int b = bh >> 3, h = bh & 7;
  int s0 = blockIdx.x * 32, d0 = blockIdx.y * 32;
  int tx = threadIdx.x, ty = threadIdx.y;
#pragma unroll
  for (int i = 0; i < 4; i++) {
    int s = ty + i * 8;
    t[s][tx] = v[(((size_t)b * Sc + s0 + s) * Hc + h) * UVc + d0 + tx];
  }
  __syncthreads();
#pragma unroll
  for (int i = 0; i < 4; i++) {
    int d = ty + i * 8;
    vT[((size_t)bh * UVc + d0 + d) * Sc + s0 + tx] = t[tx][d];
  }
}

// ---------------- attention ----------------
DEVI void stage_k_tile(short (*__restrict__ Ksm)[136], const short* __restrict__ ks,
                       int b, int h, int s0, int tid) {
  int row = tid >> 2;
  int seg = (tid & 3) * 32;
  const short* src = ks + (((size_t)b * Sc + s0 + row) * Hc + h) * Ec + seg;
  uint4 r0 = *reinterpret_cast<const uint4*>(src);
  uint4 r1 = *reinterpret_cast<const uint4*>(src + 8);
  uint4 r2 = *reinterpret_cast<const uint4*>(src + 16);
  uint4 r3 = *reinterpret_cast<const uint4*>(src + 24);
  *reinterpret_cast<uint4*>(&Ksm[row][seg]) = r0;
  *reinterpret_cast<uint4*>(&Ksm[row][seg + 8]) = r1;
  *reinterpret_cast<uint4*>(&Ksm[row][seg + 16]) = r2;
  *reinterpret_cast<uint4*>(&Ksm[row][seg + 24]) = r3;
}

DEVI void qk_scores(const short (*__restrict__ Ksm)[136], const bf16x8 (&qf)[2][4],
                    f32x4 (&d)[4][2], int lquad, int l15) {
#pragma unroll
  for (int kt = 0; kt < 4; kt++) {
    int e = kt * 32 + 4 * lquad;
#pragma unroll
    for (int sf = 0; sf < 4; sf++) {
      bf16x4 lo = *reinterpret_cast<const bf16x4*>(&Ksm[sf * 16 + l15][e]);
      bf16x4 hi = *reinterpret_cast<const bf16x4*>(&Ksm[sf * 16 + l15][e + 16]);
      bf16x8 af = __builtin_shufflevector(lo, hi, 0, 1, 2, 3, 4, 5, 6, 7);
      d[sf][0] = __builtin_amdgcn_mfma_f32_16x16x32_bf16(af, qf[0][kt], d[sf][0], 0, 0, 0);
      d[sf][1] = __builtin_amdgcn_mfma_f32_16x16x32_bf16(af, qf[1][kt], d[sf][1], 0, 0, 0);
    }
  }
}

__global__ __launch_bounds__(256, 2) void attn_kernel(
    const short* __restrict__ qs, const short* __restrict__ ks,
    const short* __restrict__ vT, const short* __restrict__ up,
    float* __restrict__ attn_out, short* __restrict__ gate) {
  __shared__ short Ks[64][136];
  __shared__ float Pl[4][64][33];
  const int bh = blockIdx.y;
  const int b = bh >> 3, h = bh & 7;
  const int l0 = blockIdx.x * 128;
  const int tid = threadIdx.x;
  const int wave = tid >> 6, lane = tid & 63;
  const int lquad = lane >> 4, l15 = lane & 15;
  const float scale = 0.08838834764831845f;  // 1/sqrt(128)

  // Q fragments (B-operand): held in registers for the whole kernel
  bf16x8 qf[2][4];
#pragma unroll
  for (int cf = 0; cf < 2; cf++) {
    int lrow = l0 + wave * 32 + cf * 16 + l15;
    const short* qp = qs + (((size_t)b * Lc + lrow) * Hc + h) * Ec;
#pragma unroll
    for (int kt = 0; kt < 4; kt++) {
      int e = kt * 32 + 4 * lquad;
      bf16x4 lo = *reinterpret_cast<const bf16x4*>(qp + e);
      bf16x4 hi = *reinterpret_cast<const bf16x4*>(qp + e + 16);
      qf[cf][kt] = __builtin_shufflevector(lo, hi, 0, 1, 2, 3, 4, 5, 6, 7);
    }
  }

  // ---- pass A: row sums of exp(scale * scores) ----
  float rs0 = 0.f, rs1 = 0.f;
  for (int s0 = 0; s0 < Sc; s0 += 64) {
    stage_k_tile(Ks, ks, b, h, s0, tid);
    __syncthreads();
    f32x4 d[4][2] = {};
    qk_scores(Ks, qf, d, lquad, l15);
#pragma unroll
    for (int sf = 0; sf < 4; sf++)
#pragma unroll
      for (int r = 0; r < 4; r++) {
        rs0 += __expf(scale * d[sf][0][r]);
        rs1 += __expf(scale * d[sf][1][r]);
      }
    __syncthreads();
  }
  rs0 += __shfl_xor(rs0, 16);
  rs0 += __shfl_xor(rs0, 32);
  rs1 += __shfl_xor(rs1, 16);
  rs1 += __shfl_xor(rs1, 32);
  const float rcp0 = 1.0f / rs0, rcp1 = 1.0f / rs1;

  // ---- pass B: recompute scores, write attn, accumulate ctx^T = V^T @ P^T ----
  f32x4 ctx[8][2] = {};
  for (int s0 = 0; s0 < Sc; s0 += 64) {
    stage_k_tile(Ks, ks, b, h, s0, tid);
    __syncthreads();
    f32x4 d[4][2] = {};
    qk_scores(Ks, qf, d, lquad, l15);
#pragma unroll
    for (int sf = 0; sf < 4; sf++)
#pragma unroll
      for (int r = 0; r < 4; r++) {
        d[sf][0][r] = __expf(scale * d[sf][0][r]) * rcp0;
        d[sf][1][r] = __expf(scale * d[sf][1][r]) * rcp1;
      }
    // stash p into per-wave LDS tile [s 64][l 32] for coalesced attn writes
#pragma unroll
    for (int sf = 0; sf < 4; sf++)
#pragma unroll
      for (int r = 0; r < 4; r++) {
        int sl = sf * 16 + 4 * lquad + r;
        Pl[wave][sl][l15] = d[sf][0][r];
        Pl[wave][sl][16 + l15] = d[sf][1][r];
      }
    __syncthreads();
    {
      int l_loc = lane >> 1, half = lane & 1;
      int lrow = l0 + wave * 32 + l_loc;
      float* arow = attn_out + ((size_t)bh * Lc + lrow) * Sc + s0 + half * 32;
#pragma unroll
      for (int c = 0; c < 8; c++) {
        float4 fv;
        fv.x = Pl[wave][half * 32 + c * 4 + 0][l_loc];
        fv.y = Pl[wave][half * 32 + c * 4 + 1][l_loc];
        fv.z = Pl[wave][half * 32 + c * 4 + 2][l_loc];
        fv.w = Pl[wave][half * 32 + c * 4 + 3][l_loc];
        *reinterpret_cast<float4*>(arow + c * 4) = fv;
      }
    }
    // PV: P^T fragments come directly from d (D-layout) under the same k-mapping
#pragma unroll
    for (int kt2 = 0; kt2 < 2; kt2++) {
      bf16x8 pb0, pb1;
#pragma unroll
      for (int r = 0; r < 4; r++) {
        pb0[r] = f2bf(d[2 * kt2][0][r]);
        pb0[4 + r] = f2bf(d[2 * kt2 + 1][0][r]);
        pb1[r] = f2bf(d[2 * kt2][1][r]);
        pb1[4 + r] = f2bf(d[2 * kt2 + 1][1][r]);
      }
#pragma unroll
      for (int df = 0; df < 8; df++) {
        int dd = df * 16 + l15;
        const short* vb = vT + ((size_t)bh * UVc + dd) * Sc + s0 + kt2 * 32 + 4 * lquad;
        bf16x4 lo = *reinterpret_cast<const bf16x4*>(vb);
        bf16x4 hi = *reinterpret_cast<const bf16x4*>(vb + 16);
        bf16x8 vf = __builtin_shufflevector(lo, hi, 0, 1, 2, 3, 4, 5, 6, 7);
        ctx[df][0] = __builtin_amdgcn_mfma_f32_16x16x32_bf16(vf, pb0, ctx[df][0], 0, 0, 0);
        ctx[df][1] = __builtin_amdgcn_mfma_f32_16x16x32_bf16(vf, pb1, ctx[df][1], 0, 0, 0);
      }
    }
    __syncthreads();
  }

  // ---- epilogue: gate = u_p * ctx, via LDS transpose in two d-halves ----
#pragma unroll
  for (int h2 = 0; h2 < 2; h2++) {
#pragma unroll
    for (int dfl = 0; dfl < 4; dfl++)
#pragma unroll
      for (int r = 0; r < 4; r++) {
        int dl = dfl * 16 + 4 * lquad + r;
        Pl[wave][dl][l15] = ctx[h2 * 4 + dfl][0][r];
        Pl[wave][dl][16 + l15] = ctx[h2 * 4 + dfl][1][r];
      }
    __syncthreads();
    {
      int l_loc = lane >> 1, half = lane & 1;
      int lrow = l0 + wave * 32 + l_loc;
      size_t blrow = (size_t)b * Lc + lrow;
      int dbase = h * UVc + h2 * 64 + half * 32;
      const short* ub = up + blrow * HEc + dbase;
      short* gp = gate + blrow * HEc + dbase;
#pragma unroll
      for (int c = 0; c < 4; c++) {
        uint4 uraw = *reinterpret_cast<const uint4*>(ub + c * 8);
        short us[8];
        *reinterpret_cast<uint4*>(us) = uraw;
        short gs[8];
#pragma unroll
        for (int i2 = 0; i2 < 8; i2++) {
          float cv = Pl[wave][half * 32 + c * 8 + i2][l_loc];
          gs[i2] = f2bf(bf2f(us[i2]) * cv);
        }
        *reinterpret_cast<uint4*>(gp + c * 8) = *reinterpret_cast<uint4*>(gs);
      }
    }
    __syncthreads();
  }
}

// ---------------- launch ----------------
extern "C" void kernel_launch(void* const* d_in, const int* in_sizes, int n_in,
                              void* d_out, int out_size, void* d_ws, size_t ws_size,
                              hipStream_t stream) {
  const float* u_in = (const float*)d_in[0];
  const float* qry = (const float*)d_in[1];
  // d_in[2] = keys : unused by the reference graph (shared qk projection)
  const float* vals = (const float*)d_in[3];
  const float* Wqk = (const float*)d_in[4];
  const float* bqk = (const float*)d_in[5];
  const float* Wv = (const float*)d_in[6];
  const float* bv = (const float*)d_in[7];
  const float* Wu = (const float*)d_in[8];
  const float* bu = (const float*)d_in[9];
  const float* Wo = (const float*)d_in[10];
  const float* bo = (const float*)d_in[11];
  const float* qg = (const float*)d_in[12];
  const float* qb = (const float*)d_in[13];
  const float* kg = (const float*)d_in[14];
  const float* kb = (const float*)d_in[15];

  char* w = (char*)d_ws;
  short* WT0 = (short*)w; w += (size_t)1024 * 1024 * 2;
  short* WT1 = (short*)w; w += (size_t)1024 * 1024 * 2;
  short* WT2 = (short*)w; w += (size_t)1024 * 1024 * 2;
  short* WT3 = (short*)w; w += (size_t)1024 * 1024 * 2;
  float* ctab = (float*)w; w += (size_t)2048 * 512 * 4;
  float* stab = (float*)w; w += (size_t)2048 * 512 * 4;
  short* qkg = (short*)w; w += (size_t)BLc * HEc * 2;
  short* qbf = (short*)w; w += (size_t)BLc * HEc * 2;
  short* kbf = (short*)w; w += (size_t)BLc * HEc * 2;
  short* vbf = (short*)w; w += (size_t)BLc * HEc * 2;
  short* vTb = (short*)w; w += (size_t)BLc * HEc * 2;
  short* upb = (short*)w; w += (size_t)BLc * HEc * 2;
  short* gtb = (short*)w; w += (size_t)BLc * HEc * 2;

  float* o_out = (float*)d_out;
  float* attn_out = o_out + (size_t)BLc * Dc;

  dim3 tb(32, 8);
  wt_trans_kernel<<<dim3(32, 32), tb, 0, stream>>>(Wqk, WT0);
  wt_trans_kernel<<<dim3(32, 32), tb, 0, stream>>>(Wv, WT1);
  wt_trans_kernel<<<dim3(32, 32), tb, 0, stream>>>(Wu, WT2);
  wt_trans_kernel<<<dim3(32, 32), tb, 0, stream>>>(Wo, WT3);
  rope_table_kernel<<<4096, 256, 0, stream>>>(ctab, stab);

  gemm_kernel<true, true><<<dim3(64, 8), 256, 0, stream>>>(qry, WT0, bqk, qkg, BLc, HEc, Dc);
  rope_apply_kernel<<<4096, 256, 0, stream>>>(qkg, ctab, stab, qg, qb, kg, kb, qbf, kbf);
  gemm_kernel<true, true><<<dim3(64, 8), 256, 0, stream>>>(vals, WT1, bv, vbf, BLc, HEc, Dc);
  vtrans_kernel<<<dim3(64, 4, 32), tb, 0, stream>>>(vbf, vTb);
  gemm_kernel<true, true><<<dim3(64, 8), 256, 0, stream>>>(u_in, WT2, bu, upb, BLc, HEc, Dc);
  attn_kernel<<<dim3(16, 32), 256, 0, stream>>>(qbf, kbf, vTb, upb, attn_out, gtb);
  gemm_kernel<false, false><<<dim3(64, 8), 256, 0, stream>>>(gtb, WT3, bo, o_out, BLc, Dc, HEc);
}

// Round 2
// 422.382 us; speedup vs baseline: 1.9664x; 1.9664x over previous
//
#include <hip/hip_runtime.h>
#include <hip/hip_bf16.h>
#include <math.h>

#define DEVI static __device__ __forceinline__

typedef __attribute__((ext_vector_type(4))) float f32x4;
typedef __attribute__((ext_vector_type(8))) short bf16x8;
typedef __attribute__((ext_vector_type(4))) short bf16x4;

constexpr int Bc = 4, Lc = 2048, Sc = 2048, Dc = 1024, Hc = 8, Ec = 128, UVc = 128;
constexpr int HEc = Hc * Ec;   // 1024
constexpr int BLc = Bc * Lc;   // 8192

DEVI unsigned f2bf_bits(float f) {
  unsigned u = __builtin_bit_cast(unsigned, f);
  return (u + 0x7FFFu + ((u >> 16) & 1u)) >> 16;
}
DEVI short f2bf(float f) { return (short)f2bf_bits(f); }
DEVI float bf2f(short s) {
  return __builtin_bit_cast(float, (unsigned)((unsigned short)s) << 16);
}
DEVI float gelu_f(float x) { return 0.5f * x * (1.0f + erff(x * 0.7071067811865476f)); }

DEVI void gload16(const void* gsrc, void* ldst) {
  __builtin_amdgcn_global_load_lds(
      (const __attribute__((address_space(1))) unsigned*)gsrc,
      (__attribute__((address_space(3))) unsigned*)(ldst), 16, 0, 0);
}

DEVI f32x4 mfma16(bf16x8 a, bf16x8 b, f32x4 c) {
  return __builtin_amdgcn_mfma_f32_16x16x32_bf16(a, b, c, 0, 0, 0);
}

// ---------------- prep: f32 -> bf16 convert (8 elems/thread) ----------------
__global__ void cvt_bf16_kernel(const float* __restrict__ in, short* __restrict__ out) {
  size_t i = ((size_t)blockIdx.x * 256 + threadIdx.x) * 8;
  float4 f1 = *reinterpret_cast<const float4*>(in + i);
  float4 f2 = *reinterpret_cast<const float4*>(in + i + 4);
  uint4 pk;
  pk.x = f2bf_bits(f1.x) | (f2bf_bits(f1.y) << 16);
  pk.y = f2bf_bits(f1.z) | (f2bf_bits(f1.w) << 16);
  pk.z = f2bf_bits(f2.x) | (f2bf_bits(f2.y) << 16);
  pk.w = f2bf_bits(f2.z) | (f2bf_bits(f2.w) << 16);
  *reinterpret_cast<uint4*>(out + i) = pk;
}

// ---------------- prep: weight transpose f32[K][N] -> bf16 WT[N][K] ----------------
__global__ void wt_trans_kernel(const float* __restrict__ W, short* __restrict__ WT) {
  __shared__ float t[32][33];
  int tx = threadIdx.x, ty = threadIdx.y;
  int n0 = blockIdx.x * 32, k0 = blockIdx.y * 32;
#pragma unroll
  for (int i = 0; i < 4; i++) {
    int r = ty + i * 8;
    t[r][tx] = W[(size_t)(k0 + r) * 1024 + n0 + tx];
  }
  __syncthreads();
#pragma unroll
  for (int i = 0; i < 4; i++) {
    int r = ty + i * 8;
    WT[(size_t)(n0 + r) * 1024 + k0 + tx] = f2bf(t[tx][r]);
  }
}

// ---------------- prep: rope tables [2048][512] ----------------
__global__ void rope_table_kernel(float* __restrict__ ct, float* __restrict__ st) {
  int idx = blockIdx.x * 256 + threadIdx.x;
  int t = idx >> 9, i = idx & 511;
  float inv = expf((float)i * (-9.210340371976184f / 512.0f));
  float ang = (float)t * inv;
  float sv, cv;
  sincosf(ang, &sv, &cv);
  ct[idx] = cv;
  st[idx] = sv;
}

// ---------------- GEMM: C = act(A @ W + bias); A bf16 [M][K], W as WT[N][K] bf16 ----------------
// 128x128 tile, BK=32, global_load_lds staging, XOR-swizzled LDS, dbuf + 1 barrier/step.
template <bool GELU_OUT>
__global__ __launch_bounds__(256, 2) void gemm_kernel(
    const short* __restrict__ A, const short* __restrict__ BT,
    const float* __restrict__ bias, void* __restrict__ Cptr, int M, int N, int K) {
  __shared__ char smem[32768];
  const int tid = threadIdx.x;
  const int wave = tid >> 6, lane = tid & 63;
  const int lquad = lane >> 4, l15 = lane & 15;
  const int m0 = blockIdx.x * 128, n0 = blockIdx.y * 128;
  const int wr = wave >> 1, wc = wave & 1;
  f32x4 acc[4][4] = {};

  // staging addresses: LDS byte q (linear) holds logical byte (q&63)^((row&3)<<4) of row q>>6
  const int q0 = tid * 16, q1 = tid * 16 + 4096;
  const int r0 = q0 >> 6, o0 = (q0 & 63) ^ ((r0 & 3) << 4);
  const int r1 = q1 >> 6, o1 = (q1 & 63) ^ ((r1 & 3) << 4);
  const short* a0 = A + (size_t)(m0 + r0) * K + (o0 >> 1);
  const short* a1 = A + (size_t)(m0 + r1) * K + (o1 >> 1);
  const short* b0 = BT + (size_t)(n0 + r0) * K + (o0 >> 1);
  const short* b1 = BT + (size_t)(n0 + r1) * K + (o1 >> 1);

#define G_STAGE(buf, kt)                                   \
  {                                                        \
    char* As_ = smem + (buf)*8192;                         \
    char* Bs_ = smem + 16384 + (buf)*8192;                 \
    gload16(a0 + (kt), As_ + q0);                          \
    gload16(a1 + (kt), As_ + q1);                          \
    gload16(b0 + (kt), Bs_ + q0);                          \
    gload16(b1 + (kt), Bs_ + q1);                          \
  }

  G_STAGE(0, 0);
  asm volatile("s_waitcnt vmcnt(0)" ::: "memory");
  __builtin_amdgcn_s_barrier();

  const int NT = K >> 5;
  for (int t = 0; t < NT; t++) {
    const int cur = t & 1;
    if (t + 1 < NT) G_STAGE(cur ^ 1, (t + 1) * 32);
    __builtin_amdgcn_sched_barrier(0);
    const char* As_ = smem + cur * 8192;
    const char* Bs_ = smem + 16384 + cur * 8192;
    const int ko = lquad * 16;
    bf16x8 a[4], b[4];
#pragma unroll
    for (int f = 0; f < 4; f++) {
      int ra = wr * 64 + f * 16 + l15;
      a[f] = *reinterpret_cast<const bf16x8*>(As_ + ra * 64 + (ko ^ ((ra & 3) << 4)));
      int rb = wc * 64 + f * 16 + l15;
      b[f] = *reinterpret_cast<const bf16x8*>(Bs_ + rb * 64 + (ko ^ ((rb & 3) << 4)));
    }
#pragma unroll
    for (int mf = 0; mf < 4; mf++)
#pragma unroll
      for (int nf = 0; nf < 4; nf++)
        acc[mf][nf] = mfma16(a[mf], b[nf], acc[mf][nf]);
    asm volatile("s_waitcnt vmcnt(0) lgkmcnt(0)" ::: "memory");
    __builtin_amdgcn_sched_barrier(0);
    __builtin_amdgcn_s_barrier();
  }
#undef G_STAGE

#pragma unroll
  for (int mf = 0; mf < 4; mf++) {
#pragma unroll
    for (int nf = 0; nf < 4; nf++) {
      int mrow = m0 + wr * 64 + mf * 16 + 4 * lquad;
      int ncol = n0 + wc * 64 + nf * 16 + l15;
      float bval = bias[ncol];
#pragma unroll
      for (int r = 0; r < 4; r++) {
        float v = acc[mf][nf][r] + bval;
        if (GELU_OUT) {
          ((short*)Cptr)[(size_t)(mrow + r) * N + ncol] = f2bf(gelu_f(v));
        } else {
          ((float*)Cptr)[(size_t)(mrow + r) * N + ncol] = v;
        }
      }
    }
  }
}

// ---------------- rope apply ----------------
__global__ void rope_apply_kernel(const short* __restrict__ qkg,
                                  const float* __restrict__ ct, const float* __restrict__ st,
                                  const float* __restrict__ qg, const float* __restrict__ qb,
                                  const float* __restrict__ kg, const float* __restrict__ kb,
                                  short* __restrict__ qo, short* __restrict__ ko) {
  int tid = blockIdx.x * 256 + threadIdx.x;
  size_t base = (size_t)tid * 8;
  int bl = (int)(base >> 10);
  int rem = (int)(base & 1023);
  int e0 = rem & 127;
  int t = bl & 2047;
  int pf = rem >> 1;
  uint4 raw = *reinterpret_cast<const uint4*>(qkg + base);
  short sh[8];
  *reinterpret_cast<uint4*>(sh) = raw;
  float4 c4 = *reinterpret_cast<const float4*>(ct + (size_t)t * 512 + pf);
  float4 s4 = *reinterpret_cast<const float4*>(st + (size_t)t * 512 + pf);
  float4 qga = *reinterpret_cast<const float4*>(qg + e0);
  float4 qgb = *reinterpret_cast<const float4*>(qg + e0 + 4);
  float4 qba = *reinterpret_cast<const float4*>(qb + e0);
  float4 qbb = *reinterpret_cast<const float4*>(qb + e0 + 4);
  float4 kga = *reinterpret_cast<const float4*>(kg + e0);
  float4 kgb = *reinterpret_cast<const float4*>(kg + e0 + 4);
  float4 kba = *reinterpret_cast<const float4*>(kb + e0);
  float4 kbb = *reinterpret_cast<const float4*>(kb + e0 + 4);
  float C[4] = {c4.x, c4.y, c4.z, c4.w};
  float Sn[4] = {s4.x, s4.y, s4.z, s4.w};
  float QG[8] = {qga.x, qga.y, qga.z, qga.w, qgb.x, qgb.y, qgb.z, qgb.w};
  float QB[8] = {qba.x, qba.y, qba.z, qba.w, qbb.x, qbb.y, qbb.z, qbb.w};
  float KG[8] = {kga.x, kga.y, kga.z, kga.w, kgb.x, kgb.y, kgb.z, kgb.w};
  float KB[8] = {kba.x, kba.y, kba.z, kba.w, kbb.x, kbb.y, kbb.z, kbb.w};
  short qsh[8], ksh[8];
#pragma unroll
  for (int j = 0; j < 4; j++) {
    float x0 = bf2f(sh[2 * j]), x1 = bf2f(sh[2 * j + 1]);
    float q0 = x0 * QG[2 * j] + QB[2 * j];
    float q1 = x1 * QG[2 * j + 1] + QB[2 * j + 1];
    qsh[2 * j] = f2bf(q0 * C[j] - q1 * Sn[j]);
    qsh[2 * j + 1] = f2bf(q1 * C[j] + q0 * Sn[j]);
    float k0v = x0 * KG[2 * j] + KB[2 * j];
    float k1v = x1 * KG[2 * j + 1] + KB[2 * j + 1];
    ksh[2 * j] = f2bf(k0v * C[j] - k1v * Sn[j]);
    ksh[2 * j + 1] = f2bf(k1v * C[j] + k0v * Sn[j]);
  }
  *reinterpret_cast<uint4*>(qo + base) = *reinterpret_cast<uint4*>(qsh);
  *reinterpret_cast<uint4*>(ko + base) = *reinterpret_cast<uint4*>(ksh);
}

// ---------------- v transpose: [B][S][H][UV] -> [B][H][UV][S] (bf16) ----------------
__global__ void vtrans_kernel(const short* __restrict__ v, short* __restrict__ vT) {
  __shared__ short t[32][33];
  int bh = blockIdx.z;
  int b = bh >> 3, h = bh & 7;
  int s0 = blockIdx.x * 32, d0 = blockIdx.y * 32;
  int tx = threadIdx.x, ty = threadIdx.y;
#pragma unroll
  for (int i = 0; i < 4; i++) {
    int s = ty + i * 8;
    t[s][tx] = v[(((size_t)b * Sc + s0 + s) * Hc + h) * UVc + d0 + tx];
  }
  __syncthreads();
#pragma unroll
  for (int i = 0; i < 4; i++) {
    int d = ty + i * 8;
    vT[((size_t)bh * UVc + d0 + d) * Sc + s0 + tx] = t[tx][d];
  }
}

// ---------------- attention ----------------
// grid 512 = 8 XCD * 4 bh * 16 lblk; per block 128 L-rows; s-tiles of 64, dbuf K+V in LDS.
__global__ __launch_bounds__(256, 2) void attn_kernel(
    const short* __restrict__ qs, const short* __restrict__ ks,
    const short* __restrict__ vT, const short* __restrict__ up,
    float* __restrict__ attn_out, short* __restrict__ gate) {
  __shared__ char smem[65536];  // K dbuf 2*16K, V dbuf 2*16K
  const int bid = blockIdx.x;
  const int xcd = bid & 7, jj = bid >> 3;
  const int bh = xcd * 4 + (jj >> 4);
  const int lblk = jj & 15;
  const int b = bh >> 3, h = bh & 7;
  const int l0 = lblk * 128;
  const int tid = threadIdx.x;
  const int wave = tid >> 6, lane = tid & 63;
  const int lquad = lane >> 4, l15 = lane & 15;
  const float scale = 0.08838834764831845f;  // 1/sqrt(128)

  // staging: K tile [64][128] (256B rows), V tile [128][64] (128B rows); swizzle ^((row&7)<<4)
  const short* ksrc[4];
  const short* vsrc[4];
  int qdst[4];
#pragma unroll
  for (int i = 0; i < 4; i++) {
    int q = i * 4096 + tid * 16;
    qdst[i] = q;
    int row = q >> 8, off = (q & 255) ^ ((row & 7) << 4);
    ksrc[i] = ks + (((size_t)b * Sc + row) * Hc + h) * Ec + (off >> 1);
    int rv = q >> 7, ov = (q & 127) ^ ((rv & 7) << 4);
    vsrc[i] = vT + ((size_t)bh * UVc + rv) * Sc + (ov >> 1);
  }

#define STAGE_K(buf, s0)                                                     \
  {                                                                          \
    char* Kb_ = smem + (buf)*16384;                                          \
    gload16(ksrc[0] + (size_t)(s0)*1024, Kb_ + qdst[0]);                     \
    gload16(ksrc[1] + (size_t)(s0)*1024, Kb_ + qdst[1]);                     \
    gload16(ksrc[2] + (size_t)(s0)*1024, Kb_ + qdst[2]);                     \
    gload16(ksrc[3] + (size_t)(s0)*1024, Kb_ + qdst[3]);                     \
  }
#define STAGE_V(buf, s0)                                                     \
  {                                                                          \
    char* Vb_ = smem + 32768 + (buf)*16384;                                  \
    gload16(vsrc[0] + (s0), Vb_ + qdst[0]);                                  \
    gload16(vsrc[1] + (s0), Vb_ + qdst[1]);                                  \
    gload16(vsrc[2] + (s0), Vb_ + qdst[2]);                                  \
    gload16(vsrc[3] + (s0), Vb_ + qdst[3]);                                  \
  }

  // Q fragments (B-operand, contiguous-k convention): 16B loads
  bf16x8 qf[2][4];
#pragma unroll
  for (int cf = 0; cf < 2; cf++) {
    int lrow = l0 + wave * 32 + cf * 16 + l15;
    const short* qp = qs + (((size_t)b * Lc + lrow) * Hc + h) * Ec;
#pragma unroll
    for (int kt = 0; kt < 4; kt++)
      qf[cf][kt] = *reinterpret_cast<const bf16x8*>(qp + kt * 32 + lquad * 8);
  }

#define QK_TILE(KBASE, d)                                                              \
  {                                                                                    \
    const char* KB_ = (KBASE);                                                         \
    _Pragma("unroll") for (int kt = 0; kt < 4; kt++) {                                 \
      _Pragma("unroll") for (int sf = 0; sf < 4; sf++) {                               \
        int row = sf * 16 + l15;                                                       \
        bf16x8 kf = *reinterpret_cast<const bf16x8*>(                                  \
            KB_ + row * 256 + ((kt * 64 + lquad * 16) ^ ((row & 7) << 4)));            \
        d[sf][0] = mfma16(kf, qf[0][kt], d[sf][0]);                                    \
        d[sf][1] = mfma16(kf, qf[1][kt], d[sf][1]);                                    \
      }                                                                                \
    }                                                                                  \
  }

  // ---- pass A: row sums of exp(scale * scores) ----
  STAGE_K(0, 0);
  asm volatile("s_waitcnt vmcnt(0)" ::: "memory");
  __builtin_amdgcn_s_barrier();
  float rs0 = 0.f, rs1 = 0.f;
  for (int t = 0; t < 32; t++) {
    const int cur = t & 1;
    if (t < 31) STAGE_K(cur ^ 1, (t + 1) * 64);
    __builtin_amdgcn_sched_barrier(0);
    f32x4 d[4][2] = {};
    QK_TILE(smem + cur * 16384, d);
#pragma unroll
    for (int sf = 0; sf < 4; sf++)
#pragma unroll
      for (int r = 0; r < 4; r++) {
        rs0 += __expf(scale * d[sf][0][r]);
        rs1 += __expf(scale * d[sf][1][r]);
      }
    asm volatile("s_waitcnt vmcnt(0) lgkmcnt(0)" ::: "memory");
    __builtin_amdgcn_sched_barrier(0);
    __builtin_amdgcn_s_barrier();
  }
  rs0 += __shfl_xor(rs0, 16);
  rs0 += __shfl_xor(rs0, 32);
  rs1 += __shfl_xor(rs1, 16);
  rs1 += __shfl_xor(rs1, 32);
  const float rcp0 = 1.0f / rs0, rcp1 = 1.0f / rs1;

  // ---- pass B: recompute scores, write attn (from regs), accumulate ctx^T = V^T @ P^T ----
  STAGE_K(0, 0);
  STAGE_V(0, 0);
  asm volatile("s_waitcnt vmcnt(0)" ::: "memory");
  __builtin_amdgcn_s_barrier();
  f32x4 ctx[8][2] = {};
  for (int t = 0; t < 32; t++) {
    const int cur = t & 1;
    const int s0 = t * 64;
    if (t < 31) {
      STAGE_K(cur ^ 1, s0 + 64);
      STAGE_V(cur ^ 1, s0 + 64);
    }
    __builtin_amdgcn_sched_barrier(0);
    f32x4 d[4][2] = {};
    QK_TILE(smem + cur * 16384, d);
#pragma unroll
    for (int sf = 0; sf < 4; sf++)
#pragma unroll
      for (int r = 0; r < 4; r++) {
        d[sf][0][r] = __expf(scale * d[sf][0][r]) * rcp0;
        d[sf][1][r] = __expf(scale * d[sf][1][r]) * rcp1;
      }
    // attn writes straight from D-registers: lane's 4 values are 4 consecutive s-cols
#pragma unroll
    for (int cf = 0; cf < 2; cf++) {
      int lrow = l0 + wave * 32 + cf * 16 + l15;
      float* arow = attn_out + ((size_t)bh * Lc + lrow) * Sc + s0 + lquad * 4;
#pragma unroll
      for (int sf = 0; sf < 4; sf++)
        *reinterpret_cast<f32x4*>(arow + sf * 16) = d[sf][cf];
    }
    // PV with split-k convention (P^T frags lane-local from d)
    const char* VB_ = smem + 32768 + cur * 16384;
#pragma unroll
    for (int c = 0; c < 2; c++) {
      bf16x8 pb0, pb1;
#pragma unroll
      for (int r = 0; r < 4; r++) {
        pb0[r] = f2bf(d[2 * c][0][r]);
        pb0[4 + r] = f2bf(d[2 * c + 1][0][r]);
        pb1[r] = f2bf(d[2 * c][1][r]);
        pb1[4 + r] = f2bf(d[2 * c + 1][1][r]);
      }
#pragma unroll
      for (int df = 0; df < 8; df++) {
        int dd = df * 16 + l15;
        int sw = (dd & 7) << 4;
        const char* vrow = VB_ + dd * 128;
        bf16x4 lo = *reinterpret_cast<const bf16x4*>(vrow + ((c * 64 + lquad * 8) ^ sw));
        bf16x4 hi = *reinterpret_cast<const bf16x4*>(vrow + ((c * 64 + 32 + lquad * 8) ^ sw));
        bf16x8 vf = __builtin_shufflevector(lo, hi, 0, 1, 2, 3, 4, 5, 6, 7);
        ctx[df][0] = mfma16(vf, pb0, ctx[df][0]);
        ctx[df][1] = mfma16(vf, pb1, ctx[df][1]);
      }
    }
    // leave the 8 attn stores in flight; drain the 8 staged loads + LDS reads
    asm volatile("s_waitcnt vmcnt(8) lgkmcnt(0)" ::: "memory");
    __builtin_amdgcn_sched_barrier(0);
    __builtin_amdgcn_s_barrier();
  }
#undef STAGE_K
#undef STAGE_V
#undef QK_TILE

  // ---- epilogue: gate = u_p * ctx, direct from regs (lane's 4 vals = 4 consecutive d) ----
#pragma unroll
  for (int cf = 0; cf < 2; cf++) {
    int lrow = l0 + wave * 32 + cf * 16 + l15;
    size_t base = ((size_t)b * Lc + lrow) * HEc + h * UVc;
    const short* ub = up + base;
    short* gp = gate + base;
#pragma unroll
    for (int df = 0; df < 8; df++) {
      int doff = df * 16 + lquad * 4;
      bf16x4 uv = *reinterpret_cast<const bf16x4*>(ub + doff);
      bf16x4 gv;
#pragma unroll
      for (int r = 0; r < 4; r++)
        gv[r] = f2bf(bf2f(uv[r]) * ctx[df][cf][r]);
      *reinterpret_cast<bf16x4*>(gp + doff) = gv;
    }
  }
}

// ---------------- launch ----------------
extern "C" void kernel_launch(void* const* d_in, const int* in_sizes, int n_in,
                              void* d_out, int out_size, void* d_ws, size_t ws_size,
                              hipStream_t stream) {
  const float* u_in = (const float*)d_in[0];
  const float* qry = (const float*)d_in[1];
  // d_in[2] = keys : unused (use_aff shared qk projection)
  const float* vals = (const float*)d_in[3];
  const float* Wqk = (const float*)d_in[4];
  const float* bqk = (const float*)d_in[5];
  const float* Wv = (const float*)d_in[6];
  const float* bv = (const float*)d_in[7];
  const float* Wu = (const float*)d_in[8];
  const float* bu = (const float*)d_in[9];
  const float* Wo = (const float*)d_in[10];
  const float* bo = (const float*)d_in[11];
  const float* qg = (const float*)d_in[12];
  const float* qb = (const float*)d_in[13];
  const float* kg = (const float*)d_in[14];
  const float* kb = (const float*)d_in[15];

  char* w = (char*)d_ws;
  short* WT0 = (short*)w; w += (size_t)1024 * 1024 * 2;
  short* WT1 = (short*)w; w += (size_t)1024 * 1024 * 2;
  short* WT2 = (short*)w; w += (size_t)1024 * 1024 * 2;
  short* WT3 = (short*)w; w += (size_t)1024 * 1024 * 2;
  float* ctab = (float*)w; w += (size_t)2048 * 512 * 4;
  float* stab = (float*)w; w += (size_t)2048 * 512 * 4;
  const size_t BUF = (size_t)BLc * HEc * 2;  // 16.78 MB
  short* C1 = (short*)w; w += BUF;   // queries bf16; later reused as v_gelu
  short* C2 = (short*)w; w += BUF;   // values bf16
  short* C3 = (short*)w; w += BUF;   // u bf16
  short* qkg = (short*)w; w += BUF;  // qk gelu out; later reused as gate
  short* qbf = (short*)w; w += BUF;
  short* kbf = (short*)w; w += BUF;
  short* vTb = (short*)w; w += BUF;
  short* upb = (short*)w; w += BUF;
  short* vgl = C1;   // alias: C1 dead after GEMM1
  short* gtb = qkg;  // alias: qkg dead after rope_apply

  float* o_out = (float*)d_out;
  float* attn_out = o_out + (size_t)BLc * Dc;

  dim3 tb(32, 8);
  cvt_bf16_kernel<<<4096, 256, 0, stream>>>(qry, C1);
  cvt_bf16_kernel<<<4096, 256, 0, stream>>>(vals, C2);
  cvt_bf16_kernel<<<4096, 256, 0, stream>>>(u_in, C3);
  wt_trans_kernel<<<dim3(32, 32), tb, 0, stream>>>(Wqk, WT0);
  wt_trans_kernel<<<dim3(32, 32), tb, 0, stream>>>(Wv, WT1);
  wt_trans_kernel<<<dim3(32, 32), tb, 0, stream>>>(Wu, WT2);
  wt_trans_kernel<<<dim3(32, 32), tb, 0, stream>>>(Wo, WT3);
  rope_table_kernel<<<4096, 256, 0, stream>>>(ctab, stab);

  gemm_kernel<true><<<dim3(64, 8), 256, 0, stream>>>(C1, WT0, bqk, qkg, BLc, HEc, Dc);
  rope_apply_kernel<<<4096, 256, 0, stream>>>(qkg, ctab, stab, qg, qb, kg, kb, qbf, kbf);
  gemm_kernel<true><<<dim3(64, 8), 256, 0, stream>>>(C2, WT1, bv, vgl, BLc, HEc, Dc);
  vtrans_kernel<<<dim3(64, 4, 32), tb, 0, stream>>>(vgl, vTb);
  gemm_kernel<true><<<dim3(64, 8), 256, 0, stream>>>(C3, WT2, bu, upb, BLc, HEc, Dc);
  attn_kernel<<<512, 256, 0, stream>>>(qbf, kbf, vTb, upb, attn_out, gtb);
  gemm_kernel<false><<<dim3(64, 8), 256, 0, stream>>>(gtb, WT3, bo, o_out, BLc, Dc, HEc);
}